// Round 4
// baseline (1401.249 us; speedup 1.0000x reference)
//
#include <hip/hip_runtime.h>
#include <hip/hip_bf16.h>

typedef unsigned short u16;
typedef __bf16 bf16x8 __attribute__((ext_vector_type(8)));
typedef float f32x4 __attribute__((ext_vector_type(4)));
typedef u16 u16x8 __attribute__((ext_vector_type(8)));

// ---------- helpers ----------
__device__ __forceinline__ float bf2f(u16 u) {
    unsigned x = ((unsigned)u) << 16;
    return __builtin_bit_cast(float, x);
}
__device__ __forceinline__ u16 f2bf(float f) {  // round-to-nearest-even
    unsigned x = __builtin_bit_cast(unsigned, f);
    unsigned r = (x + 0x7fffu + ((x >> 16) & 1u)) >> 16;
    return (u16)r;
}
__device__ __forceinline__ float sigm(float x) {
    return __builtin_amdgcn_rcpf(1.f + __expf(-x));
}
__device__ __forceinline__ float tanh_fast(float x) {
    return 1.f - 2.f * __builtin_amdgcn_rcpf(1.f + __expf(2.f * x));
}

// ---------- weight concat + fp32->bf16 convert ----------
__global__ void convw_kernel(const float* __restrict__ wf, const float* __restrict__ wr,
                             u16* __restrict__ out, int half_rows, int K) {
    int idx = blockIdx.x * 256 + threadIdx.x;
    int total = 2 * half_rows * K;
    if (idx >= total) return;
    int n = idx / K, k = idx - n * K;
    float v = (n < half_rows) ? wf[(size_t)n * K + k] : wr[(size_t)(n - half_rows) * K + k];
    out[idx] = f2bf(v);
}

// ---------- bf16 MFMA GEMM, C = A(MxK) * B^T (B is NxK row-major), C bf16 ----------
template <bool AF32>
__global__ __launch_bounds__(256, 2) void gemm_bf16_bt(const void* __restrict__ Av,
                                                       const u16* __restrict__ B,
                                                       u16* __restrict__ C,
                                                       int M, int N, int K) {
    __shared__ __align__(16) u16 As[128 * 40];
    __shared__ __align__(16) u16 Bs[128 * 40];
    const int tid = threadIdx.x;
    const int n0 = blockIdx.x * 128, m0 = blockIdx.y * 128;
    const int srow = tid >> 1, shalf = tid & 1;
    const int lane = tid & 63, wv = tid >> 6;
    const int wm = wv >> 1, wn = wv & 1;
    const int frow = lane & 15, fko = (lane >> 4) * 8;
    f32x4 acc[4][4] = {};
    const int nk = K >> 5;
    for (int kt = 0; kt < nk; ++kt) {
        u16x8 a0, a1;
        if (AF32) {
            const float* ap = (const float*)Av + (size_t)(m0 + srow) * K + kt * 32 + shalf * 16;
            f32x4 f0 = *(const f32x4*)(ap);
            f32x4 f1 = *(const f32x4*)(ap + 4);
            f32x4 f2 = *(const f32x4*)(ap + 8);
            f32x4 f3 = *(const f32x4*)(ap + 12);
#pragma unroll
            for (int x = 0; x < 4; x++) {
                a0[x] = f2bf(f0[x]); a0[4 + x] = f2bf(f1[x]);
                a1[x] = f2bf(f2[x]); a1[4 + x] = f2bf(f3[x]);
            }
        } else {
            const u16* ap = (const u16*)Av + (size_t)(m0 + srow) * K + kt * 32 + shalf * 16;
            a0 = *(const u16x8*)(ap);
            a1 = *(const u16x8*)(ap + 8);
        }
        const u16* bp = B + (size_t)(n0 + srow) * K + kt * 32 + shalf * 16;
        u16x8 b0 = *(const u16x8*)(bp);
        u16x8 b1 = *(const u16x8*)(bp + 8);
        __syncthreads();
        *(u16x8*)&As[srow * 40 + shalf * 16] = a0;
        *(u16x8*)&As[srow * 40 + shalf * 16 + 8] = a1;
        *(u16x8*)&Bs[srow * 40 + shalf * 16] = b0;
        *(u16x8*)&Bs[srow * 40 + shalf * 16 + 8] = b1;
        __syncthreads();
        bf16x8 af[4], bfr[4];
#pragma unroll
        for (int mi = 0; mi < 4; mi++)
            af[mi] = *(const bf16x8*)&As[(wm * 64 + mi * 16 + frow) * 40 + fko];
#pragma unroll
        for (int ni = 0; ni < 4; ni++)
            bfr[ni] = *(const bf16x8*)&Bs[(wn * 64 + ni * 16 + frow) * 40 + fko];
#pragma unroll
        for (int mi = 0; mi < 4; mi++)
#pragma unroll
            for (int ni = 0; ni < 4; ni++)
                acc[mi][ni] = __builtin_amdgcn_mfma_f32_16x16x32_bf16(af[mi], bfr[ni], acc[mi][ni], 0, 0, 0);
    }
#pragma unroll
    for (int mi = 0; mi < 4; mi++)
#pragma unroll
        for (int ni = 0; ni < 4; ni++)
#pragma unroll
            for (int r = 0; r < 4; r++) {
                int row = m0 + wm * 64 + mi * 16 + (lane >> 4) * 4 + r;
                int col = n0 + wn * 64 + ni * 16 + (lane & 15);
                C[(size_t)row * N + col] = f2bf(acc[mi][ni][r]);
            }
}

// ---------- LSTM recurrence via MFMA: block = 8 batches x 1 direction ----------
// A-tile rows 4g,4g+1 (g=0..3) hold batches 2g,2g+1; other rows stay zero.
// C-layout: lane (g=l>>4, col=l&15) holds gate gt of (batch 2g+r, j=64*jg+16*w+col)
// in acc[2*gt+jg][r] -> pointwise is fully in-lane, NO shuffles. All 64 lanes
// run 4 independent (r,jg) chains. Raw s_barrier with lgkm-only drain; 2-deep
// register x-prefetch; unroll-2 for static LDS buffer indices.
__global__ __launch_bounds__(256, 1) void lstm_mfma(const u16* __restrict__ xproj,
                                                    const float* __restrict__ whh_f,
                                                    const float* __restrict__ whh_r,
                                                    const float* __restrict__ bih_f,
                                                    const float* __restrict__ bhh_f,
                                                    const float* __restrict__ bih_r,
                                                    const float* __restrict__ bhh_r,
                                                    u16* __restrict__ hout) {
    const int q = blockIdx.x;  // batches 8q..8q+7
    const int d = blockIdx.y;
    const int tid = threadIdx.x;
    const int w = tid >> 6, l = tid & 63;
    const float* whh = d ? whh_r : whh_f;
    const float* bih = d ? bih_r : bih_f;
    const float* bhh = d ? bhh_r : bhh_f;

    // B-fragments: tile k covers gate-rows [(w+4k)*16,+16); k=2*gt+jg
    bf16x8 bf[8][4];
#pragma unroll
    for (int k = 0; k < 8; ++k) {
        const float* wr = whh + (size_t)((w + 4 * k) * 16 + (l & 15)) * 128;
#pragma unroll
        for (int c = 0; c < 4; ++c) {
            f32x4 x0 = *(const f32x4*)(wr + c * 32 + (l >> 4) * 8);
            f32x4 x1 = *(const f32x4*)(wr + c * 32 + (l >> 4) * 8 + 4);
            u16x8 t;
#pragma unroll
            for (int x = 0; x < 4; x++) { t[x] = f2bf(x0[x]); t[4 + x] = f2bf(x1[x]); }
            bf[k][c] = __builtin_bit_cast(bf16x8, t);
        }
    }

    const int col = l & 15, g = l >> 4;
    // bias[jg][gt] for j = 64*jg + 16*w + col
    float bias[2][4];
#pragma unroll
    for (int jg = 0; jg < 2; jg++)
#pragma unroll
        for (int gt = 0; gt < 4; gt++) {
            int j = 64 * jg + 16 * w + col;
            bias[jg][gt] = bih[gt * 128 + j] + bhh[gt * 128 + j];
        }

    __shared__ __align__(16) u16 h_lds[2][16 * 136];
    for (int i = tid; i < 2 * 16 * 136; i += 256) ((u16*)h_lds)[i] = 0;

    // x base for batch 8q+2g (+r*512*1024 for r=1)
    const u16* xb0 = xproj + ((size_t)(8 * q + 2 * g) * 512) * 1024 + (size_t)d * 512 + 16 * w + col;
    u16 xv_e[16], xv_o[16];  // [r*8 + jg*4 + gt]
    {
        const int t0 = d ? 511 : 0;
        const int t1 = d ? 510 : 1;
#pragma unroll
        for (int r = 0; r < 2; r++)
#pragma unroll
            for (int jg = 0; jg < 2; jg++)
#pragma unroll
                for (int gt = 0; gt < 4; gt++) {
                    size_t off = (size_t)r * 512 * 1024 + (size_t)gt * 128 + 64 * jg;
                    xv_e[r * 8 + jg * 4 + gt] = xb0[(size_t)t0 * 1024 + off];
                    xv_o[r * 8 + jg * 4 + gt] = xb0[(size_t)t1 * 1024 + off];
                }
    }
    float cs[2][2] = {};
    u16* ho0 = hout + ((size_t)(8 * q + 2 * g) * 512) * 256 + (size_t)d * 128 + 16 * w + col;
    __syncthreads();

#define LSTM_STEP(BUF_R, BUF_W, XV, S_CUR, S_PRE)                                              \
    {                                                                                          \
        const int tt = d ? (511 - (S_CUR)) : (S_CUR);                                          \
        bf16x8 af[4];                                                                          \
        _Pragma("unroll") for (int c = 0; c < 4; ++c)                                          \
            af[c] = *(const bf16x8*)&h_lds[BUF_R][(l & 15) * 136 + c * 32 + (l >> 4) * 8];     \
        f32x4 acc[8];                                                                          \
        _Pragma("unroll") for (int k = 0; k < 8; ++k)                                          \
            acc[k] = __builtin_amdgcn_mfma_f32_16x16x32_bf16(af[0], bf[k][0],                  \
                                                             (f32x4){0.f, 0.f, 0.f, 0.f}, 0, 0, 0); \
        _Pragma("unroll") for (int c = 1; c < 4; ++c)                                          \
            _Pragma("unroll") for (int k = 0; k < 8; ++k)                                      \
                acc[k] = __builtin_amdgcn_mfma_f32_16x16x32_bf16(af[c], bf[k][c], acc[k], 0, 0, 0); \
        _Pragma("unroll") for (int r = 0; r < 2; r++)                                          \
            _Pragma("unroll") for (int jg = 0; jg < 2; jg++) {                                 \
                float gv0 = acc[0 + jg][r] + bf2f(XV[r * 8 + jg * 4 + 0]) + bias[jg][0];       \
                float gv1 = acc[2 + jg][r] + bf2f(XV[r * 8 + jg * 4 + 1]) + bias[jg][1];       \
                float gv2 = acc[4 + jg][r] + bf2f(XV[r * 8 + jg * 4 + 2]) + bias[jg][2];       \
                float gv3 = acc[6 + jg][r] + bf2f(XV[r * 8 + jg * 4 + 3]) + bias[jg][3];       \
                cs[r][jg] = sigm(gv1) * cs[r][jg] + sigm(gv0) * tanh_fast(gv2);                \
                float hh = sigm(gv3) * tanh_fast(cs[r][jg]);                                   \
                u16 hb = f2bf(hh);                                                             \
                h_lds[BUF_W][(g * 4 + r) * 136 + 64 * jg + 16 * w + col] = hb;                 \
                ho0[(size_t)r * 512 * 256 + (size_t)tt * 256 + 64 * jg] = hb;                  \
            }                                                                                  \
        {                                                                                      \
            const int sp = (S_PRE) & 511;                                                      \
            const int tp = d ? (511 - sp) : sp;                                                \
            _Pragma("unroll") for (int r = 0; r < 2; r++)                                      \
                _Pragma("unroll") for (int jg = 0; jg < 2; jg++)                               \
                    _Pragma("unroll") for (int gt = 0; gt < 4; gt++)                           \
                        XV[r * 8 + jg * 4 + gt] =                                              \
                            xb0[(size_t)tp * 1024 + (size_t)r * 512 * 1024 +                   \
                                (size_t)gt * 128 + 64 * jg];                                   \
        }                                                                                      \
        asm volatile("s_waitcnt lgkmcnt(0)" ::: "memory");                                     \
        __builtin_amdgcn_sched_barrier(0);                                                     \
        __builtin_amdgcn_s_barrier();                                                          \
        __builtin_amdgcn_sched_barrier(0);                                                     \
    }

    for (int s = 0; s < 512; s += 2) {
        LSTM_STEP(0, 1, xv_e, s, s + 2)
        LSTM_STEP(1, 0, xv_o, s + 1, s + 3)
    }
#undef LSTM_STEP
}

// ---------- emissions ----------
__global__ __launch_bounds__(256) void em_kernel(const u16* __restrict__ h1,
                                                 const float* __restrict__ lw,
                                                 const float* __restrict__ lb,
                                                 float* __restrict__ em) {
    __shared__ float w[11 * 256];
    for (int i = threadIdx.x; i < 11 * 256; i += 256) w[i] = lw[i];
    __syncthreads();
    int r = blockIdx.x * 256 + threadIdx.x;
    const u16x8* hp = (const u16x8*)(h1 + (size_t)r * 256);
    float acc[11];
#pragma unroll
    for (int j = 0; j < 11; j++) acc[j] = lb[j];
    for (int kc = 0; kc < 32; ++kc) {
        u16x8 hv = hp[kc];
        float hf[8];
#pragma unroll
        for (int x = 0; x < 8; x++) hf[x] = bf2f(hv[x]);
#pragma unroll
        for (int x = 0; x < 8; x++)
#pragma unroll
            for (int j = 0; j < 11; j++) acc[j] = fmaf(hf[x], w[j * 256 + kc * 8 + x], acc[j]);
    }
    int b = r >> 9, t = r & 511;
    float* o = em + ((size_t)t * 64 + b) * 16;
#pragma unroll
    for (int j = 0; j < 11; j++) o[j] = acc[j];
}

// ---------- CRF ----------
__global__ __launch_bounds__(64) void crf_kernel(const float* __restrict__ em,
                                                 const int* __restrict__ tags,
                                                 const float* __restrict__ start_trans,
                                                 const float* __restrict__ end_trans,
                                                 const float* __restrict__ trans,
                                                 float* __restrict__ pb) {
    const int lane = threadIdx.x;
    const int seg = lane >> 4, kp = lane & 15;
    const int kpc = kp < 11 ? kp : 10;
    const int b = blockIdx.x * 4 + seg;
    const int* tg = tags + (size_t)b * 512;
    float num = 0.f;
    for (int t = kp; t < 512; t += 16) {
        int cur = tg[t];
        float e = em[((size_t)t * 64 + b) * 16 + cur];
        float tr = (t == 0) ? start_trans[cur] : trans[tg[t - 1] * 11 + cur];
        num += e + tr;
    }
#pragma unroll
    for (int off = 8; off >= 1; off >>= 1) num += __shfl_down(num, off, 16);
    float trcol[11];
#pragma unroll
    for (int k = 0; k < 11; k++) trcol[k] = trans[k * 11 + kpc];
    float s = start_trans[kpc] + em[(size_t)b * 16 + kpc];
    float em_nxt = em[((size_t)1 * 64 + b) * 16 + kpc];
    for (int t = 1; t < 512; ++t) {
        float em_t = em_nxt;
        int tn = (t + 1 < 512) ? t + 1 : t;
        em_nxt = em[((size_t)tn * 64 + b) * 16 + kpc];
        float v[11], m = -1e30f;
#pragma unroll
        for (int k = 0; k < 11; k++) {
            v[k] = __shfl(s, k, 16) + trcol[k];
            m = fmaxf(m, v[k]);
        }
        float sum = 0.f;
#pragma unroll
        for (int k = 0; k < 11; k++) sum += __expf(v[k] - m);
        s = m + __logf(sum) + em_t;
    }
    float u = s + end_trans[kpc];
    float m2 = -1e30f, vv[11];
#pragma unroll
    for (int k = 0; k < 11; k++) {
        vv[k] = __shfl(u, k, 16);
        m2 = fmaxf(m2, vv[k]);
    }
    float s2 = 0.f;
#pragma unroll
    for (int k = 0; k < 11; k++) s2 += __expf(vv[k] - m2);
    float den = m2 + __logf(s2);
    if (kp == 0) {
        float numt = num + end_trans[tg[511]];
        pb[b] = numt - den;
    }
}

__global__ __launch_bounds__(64) void final_kernel(const float* __restrict__ pb, float* __restrict__ out) {
    float v = pb[threadIdx.x];
#pragma unroll
    for (int off = 32; off >= 1; off >>= 1) v += __shfl_down(v, off, 64);
    if (threadIdx.x == 0) out[0] = -(v / 64.f);
}

// ---------- launch ----------
extern "C" void kernel_launch(void* const* d_in, const int* in_sizes, int n_in,
                              void* d_out, int out_size, void* d_ws, size_t ws_size,
                              hipStream_t stream) {
    const float* embeds = (const float*)d_in[0];
    const int* tags = (const int*)d_in[1];
    const float* wih0f = (const float*)d_in[3];
    const float* whh0f = (const float*)d_in[4];
    const float* bih0f = (const float*)d_in[5];
    const float* bhh0f = (const float*)d_in[6];
    const float* wih0r = (const float*)d_in[7];
    const float* whh0r = (const float*)d_in[8];
    const float* bih0r = (const float*)d_in[9];
    const float* bhh0r = (const float*)d_in[10];
    const float* wih1f = (const float*)d_in[11];
    const float* whh1f = (const float*)d_in[12];
    const float* bih1f = (const float*)d_in[13];
    const float* bhh1f = (const float*)d_in[14];
    const float* wih1r = (const float*)d_in[15];
    const float* whh1r = (const float*)d_in[16];
    const float* bih1r = (const float*)d_in[17];
    const float* bhh1r = (const float*)d_in[18];
    const float* lw = (const float*)d_in[19];
    const float* lb = (const float*)d_in[20];
    const float* st = (const float*)d_in[21];
    const float* et = (const float*)d_in[22];
    const float* tr = (const float*)d_in[23];
    float* out = (float*)d_out;

    char* ws = (char*)d_ws;
    u16* xproj = (u16*)(ws + 0);            // 64MB
    u16* h0 = (u16*)(ws + 67108864);        // 16MB
    u16* h1 = (u16*)(ws + 83886080);        // 16MB
    float* em = (float*)(ws + 100663296);   // 2MB
    u16* w0c = (u16*)(ws + 102760448);
    u16* w1c = (u16*)(ws + 104333312);
    float* pb = (float*)(ws + 104857600);

    convw_kernel<<<3072, 256, 0, stream>>>(wih0f, wih0r, w0c, 512, 768);
    convw_kernel<<<1024, 256, 0, stream>>>(wih1f, wih1r, w1c, 512, 256);
    gemm_bf16_bt<true><<<dim3(8, 256), 256, 0, stream>>>(embeds, w0c, xproj, 32768, 1024, 768);
    lstm_mfma<<<dim3(8, 2), 256, 0, stream>>>(xproj, whh0f, whh0r, bih0f, bhh0f, bih0r, bhh0r, h0);
    gemm_bf16_bt<false><<<dim3(8, 256), 256, 0, stream>>>(h0, w1c, xproj, 32768, 1024, 256);
    lstm_mfma<<<dim3(8, 2), 256, 0, stream>>>(xproj, whh1f, whh1r, bih1f, bhh1f, bih1r, bhh1r, h1);
    em_kernel<<<128, 256, 0, stream>>>(h1, lw, lb, em);
    crf_kernel<<<16, 64, 0, stream>>>(em, tags, st, et, tr, pb);
    final_kernel<<<1, 64, 0, stream>>>(pb, out);
}

// Round 5
// 1228.185 us; speedup vs baseline: 1.1409x; 1.1409x over previous
//
#include <hip/hip_runtime.h>
#include <hip/hip_bf16.h>

typedef unsigned short u16;
typedef __bf16 bf16x8 __attribute__((ext_vector_type(8)));
typedef float f32x4 __attribute__((ext_vector_type(4)));
typedef u16 u16x8 __attribute__((ext_vector_type(8)));

// ---------- helpers ----------
__device__ __forceinline__ float bf2f(u16 u) {
    unsigned x = ((unsigned)u) << 16;
    return __builtin_bit_cast(float, x);
}
__device__ __forceinline__ u16 f2bf(float f) {  // round-to-nearest-even
    unsigned x = __builtin_bit_cast(unsigned, f);
    unsigned r = (x + 0x7fffu + ((x >> 16) & 1u)) >> 16;
    return (u16)r;
}
__device__ __forceinline__ float sigm(float x) {
    return __builtin_amdgcn_rcpf(1.f + __expf(-x));
}
__device__ __forceinline__ float tanh_fast(float x) {
    return 1.f - 2.f * __builtin_amdgcn_rcpf(1.f + __expf(2.f * x));
}
__device__ __forceinline__ void gload16(const void* g, void* l) {
    __builtin_amdgcn_global_load_lds((const __attribute__((address_space(1))) void*)g,
                                     (__attribute__((address_space(3))) void*)l, 16, 0, 0);
}

// ---------- weight concat + fp32->bf16 convert ----------
__global__ void convw_kernel(const float* __restrict__ wf, const float* __restrict__ wr,
                             u16* __restrict__ out, int half_rows, int K) {
    int idx = blockIdx.x * 256 + threadIdx.x;
    int total = 2 * half_rows * K;
    if (idx >= total) return;
    int n = idx / K, k = idx - n * K;
    float v = (n < half_rows) ? wf[(size_t)n * K + k] : wr[(size_t)(n - half_rows) * K + k];
    out[idx] = f2bf(v);
}

// ---------- m97-style MFMA GEMM: C = A(MxK) * B^T (B NxK), global_load_lds staging ----------
// AF32: A is fp32 (staged raw to LDS, converted at frag read); else A is bf16.
template <bool AF32>
__global__ __launch_bounds__(256, 2) void gemm_lds(const void* __restrict__ Av,
                                                   const u16* __restrict__ B,
                                                   u16* __restrict__ C,
                                                   int M, int N, int K) {
    __shared__ __align__(16) char As[AF32 ? 16384 : 8192];  // [128][32] f32 or u16
    __shared__ __align__(16) char Bs[8192];                 // [128][32] u16
    const int tid = threadIdx.x;
    const int n0 = blockIdx.x * 128, m0 = blockIdx.y * 128;
    const int lane = tid & 63, wv = tid >> 6;
    const int wm = wv >> 1, wn = wv & 1;
    const int frow = lane & 15, fko = (lane >> 4) * 8;
    f32x4 acc[4][4] = {};
    const int nk = K >> 5;
    for (int kt = 0; kt < nk; ++kt) {
        if (AF32) {
#pragma unroll
            for (int i = 0; i < 4; ++i) {
                int s2 = tid + 256 * i;
                int r = s2 >> 3, u = s2 & 7;  // 8x16B slots per 128B row
                gload16((const float*)Av + (size_t)(m0 + r) * K + kt * 32 + u * 4, As + s2 * 16);
            }
        } else {
#pragma unroll
            for (int i = 0; i < 2; ++i) {
                int s2 = tid + 256 * i;
                int r = s2 >> 2, u = s2 & 3;  // 4x16B slots per 64B row
                gload16((const u16*)Av + (size_t)(m0 + r) * K + kt * 32 + u * 8, As + s2 * 16);
            }
        }
#pragma unroll
        for (int i = 0; i < 2; ++i) {
            int s2 = tid + 256 * i;
            int r = s2 >> 2, u = s2 & 3;
            gload16(B + (size_t)(n0 + r) * K + kt * 32 + u * 8, Bs + s2 * 16);
        }
        __syncthreads();
        bf16x8 af[4], bfr[4];
#pragma unroll
        for (int mi = 0; mi < 4; mi++) {
            int R = wm * 64 + mi * 16 + frow;
            if (AF32) {
                const float* ap = (const float*)As + R * 32 + fko;
                f32x4 v0 = *(const f32x4*)ap;
                f32x4 v1 = *(const f32x4*)(ap + 4);
                u16x8 t;
#pragma unroll
                for (int x = 0; x < 4; x++) { t[x] = f2bf(v0[x]); t[4 + x] = f2bf(v1[x]); }
                af[mi] = __builtin_bit_cast(bf16x8, t);
            } else {
                af[mi] = *(const bf16x8*)((const u16*)As + R * 32 + fko);
            }
        }
#pragma unroll
        for (int ni = 0; ni < 4; ni++)
            bfr[ni] = *(const bf16x8*)((const u16*)Bs + (wn * 64 + ni * 16 + frow) * 32 + fko);
#pragma unroll
        for (int mi = 0; mi < 4; mi++)
#pragma unroll
            for (int ni = 0; ni < 4; ni++)
                acc[mi][ni] = __builtin_amdgcn_mfma_f32_16x16x32_bf16(af[mi], bfr[ni], acc[mi][ni], 0, 0, 0);
        __syncthreads();
    }
    // epilogue: C/D layout col=lane&15, row=(lane>>4)*4+reg (m89-verified)
#pragma unroll
    for (int mi = 0; mi < 4; mi++)
#pragma unroll
        for (int ni = 0; ni < 4; ni++)
#pragma unroll
            for (int r = 0; r < 4; r++) {
                int row = m0 + wm * 64 + mi * 16 + (lane >> 4) * 4 + r;
                int col = n0 + wn * 64 + ni * 16 + (lane & 15);
                C[(size_t)row * N + col] = f2bf(acc[mi][ni][r]);
            }
}

// ---------- LSTM recurrence via MFMA: block = 2 batches x 1 direction (round-3 winner) ----------
__global__ __launch_bounds__(256, 1) void lstm_mfma(const u16* __restrict__ xproj,
                                                    const float* __restrict__ whh_f,
                                                    const float* __restrict__ whh_r,
                                                    const float* __restrict__ bih_f,
                                                    const float* __restrict__ bhh_f,
                                                    const float* __restrict__ bih_r,
                                                    const float* __restrict__ bhh_r,
                                                    u16* __restrict__ hout) {
    const int p = blockIdx.x;  // batch pair: batches 2p, 2p+1
    const int d = blockIdx.y;
    const int tid = threadIdx.x;
    const int w = tid >> 6, l = tid & 63;
    const float* whh = d ? whh_r : whh_f;
    const float* bih = d ? bih_r : bih_f;
    const float* bhh = d ? bhh_r : bhh_f;

    bf16x8 bf[8][4];
#pragma unroll
    for (int k = 0; k < 8; ++k) {
        const float* wr = whh + (size_t)((w + 4 * k) * 16 + (l & 15)) * 128;
#pragma unroll
        for (int c = 0; c < 4; ++c) {
            f32x4 x0 = *(const f32x4*)(wr + c * 32 + (l >> 4) * 8);
            f32x4 x1 = *(const f32x4*)(wr + c * 32 + (l >> 4) * 8 + 4);
            u16x8 t;
#pragma unroll
            for (int x = 0; x < 4; x++) { t[x] = f2bf(x0[x]); t[4 + x] = f2bf(x1[x]); }
            bf[k][c] = __builtin_bit_cast(bf16x8, t);
        }
    }

    const int jcol = l & 15, jg = (l >> 4) & 1, b = l >> 5;
    const int j = jg * 64 + w * 16 + jcol;
    float bias[4];
#pragma unroll
    for (int gt = 0; gt < 4; gt++) bias[gt] = bih[gt * 128 + j] + bhh[gt * 128 + j];

    __shared__ __align__(16) u16 h_lds[2][16 * 136];
    for (int i = tid; i < 2 * 16 * 136; i += 256) ((u16*)h_lds)[i] = 0;

    const u16* xb = xproj + (size_t)(2 * p + b) * 512 * 1024 + (size_t)d * 512 + j;
    u16 xv_e[4], xv_o[4];
    {
        const int t0 = d ? 511 : 0;
        const int t1 = d ? 510 : 1;
#pragma unroll
        for (int gt = 0; gt < 4; gt++) {
            xv_e[gt] = xb[(size_t)t0 * 1024 + gt * 128];
            xv_o[gt] = xb[(size_t)t1 * 1024 + gt * 128];
        }
    }
    float c_state = 0.f;
    u16* ho = hout + (size_t)(2 * p + b) * 512 * 256 + (size_t)d * 128 + j;
    __syncthreads();

#define LSTM_STEP(BUF_R, BUF_W, XV, S_CUR, S_PRE)                                              \
    {                                                                                          \
        const int tt = d ? (511 - (S_CUR)) : (S_CUR);                                          \
        bf16x8 af[4];                                                                          \
        _Pragma("unroll") for (int c = 0; c < 4; ++c)                                          \
            af[c] = *(const bf16x8*)&h_lds[BUF_R][(l & 15) * 136 + c * 32 + (l >> 4) * 8];     \
        f32x4 acc[8];                                                                          \
        _Pragma("unroll") for (int k = 0; k < 8; ++k)                                          \
            acc[k] = __builtin_amdgcn_mfma_f32_16x16x32_bf16(af[0], bf[k][0],                  \
                                                             (f32x4){0.f, 0.f, 0.f, 0.f}, 0, 0, 0); \
        _Pragma("unroll") for (int c = 1; c < 4; ++c)                                          \
            _Pragma("unroll") for (int k = 0; k < 8; ++k)                                      \
                acc[k] = __builtin_amdgcn_mfma_f32_16x16x32_bf16(af[c], bf[k][c], acc[k], 0, 0, 0); \
        float gval[4];                                                                         \
        _Pragma("unroll") for (int gt = 0; gt < 4; gt++) {                                     \
            float x00 = __shfl(acc[2 * gt][0], jcol, 64);                                      \
            float x10 = __shfl(acc[2 * gt + 1][0], jcol, 64);                                  \
            float x01 = __shfl(acc[2 * gt][1], jcol, 64);                                      \
            float x11 = __shfl(acc[2 * gt + 1][1], jcol, 64);                                  \
            float xa = jg ? x10 : x00;                                                         \
            float xc = jg ? x11 : x01;                                                         \
            gval[gt] = (b ? xc : xa) + bf2f(XV[gt]) + bias[gt];                                \
        }                                                                                      \
        {                                                                                      \
            const int sp = (S_PRE) & 511;                                                      \
            const int tp = d ? (511 - sp) : sp;                                                \
            _Pragma("unroll") for (int gt = 0; gt < 4; gt++)                                   \
                XV[gt] = xb[(size_t)tp * 1024 + gt * 128];                                     \
        }                                                                                      \
        float ip = sigm(gval[0]), fp = sigm(gval[1]);                                          \
        float tg = tanh_fast(gval[2]), op = sigm(gval[3]);                                     \
        c_state = fp * c_state + ip * tg;                                                      \
        float hh = op * tanh_fast(c_state);                                                    \
        u16 hb = f2bf(hh);                                                                     \
        h_lds[BUF_W][b * 136 + j] = hb;                                                        \
        ho[(size_t)tt * 256] = hb;                                                             \
        asm volatile("s_waitcnt lgkmcnt(0)" ::: "memory");                                     \
        __builtin_amdgcn_sched_barrier(0);                                                     \
        __builtin_amdgcn_s_barrier();                                                          \
        __builtin_amdgcn_sched_barrier(0);                                                     \
    }

    for (int s = 0; s < 512; s += 2) {
        LSTM_STEP(0, 1, xv_e, s, s + 2)
        LSTM_STEP(1, 0, xv_o, s + 1, s + 3)
    }
#undef LSTM_STEP
}

// ---------- emissions ----------
__global__ __launch_bounds__(256) void em_kernel(const u16* __restrict__ h1,
                                                 const float* __restrict__ lw,
                                                 const float* __restrict__ lb,
                                                 float* __restrict__ em) {
    __shared__ float w[11 * 256];
    for (int i = threadIdx.x; i < 11 * 256; i += 256) w[i] = lw[i];
    __syncthreads();
    int r = blockIdx.x * 256 + threadIdx.x;
    const u16x8* hp = (const u16x8*)(h1 + (size_t)r * 256);
    float acc[11];
#pragma unroll
    for (int j = 0; j < 11; j++) acc[j] = lb[j];
    for (int kc = 0; kc < 32; ++kc) {
        u16x8 hv = hp[kc];
        float hf[8];
#pragma unroll
        for (int x = 0; x < 8; x++) hf[x] = bf2f(hv[x]);
#pragma unroll
        for (int x = 0; x < 8; x++)
#pragma unroll
            for (int j = 0; j < 11; j++) acc[j] = fmaf(hf[x], w[j * 256 + kc * 8 + x], acc[j]);
    }
    int b = r >> 9, t = r & 511;
    float* o = em + ((size_t)t * 64 + b) * 16;
#pragma unroll
    for (int j = 0; j < 11; j++) o[j] = acc[j];
}

// ---------- CRF ----------
__global__ __launch_bounds__(64) void crf_kernel(const float* __restrict__ em,
                                                 const int* __restrict__ tags,
                                                 const float* __restrict__ start_trans,
                                                 const float* __restrict__ end_trans,
                                                 const float* __restrict__ trans,
                                                 float* __restrict__ pb) {
    const int lane = threadIdx.x;
    const int seg = lane >> 4, kp = lane & 15;
    const int kpc = kp < 11 ? kp : 10;
    const int b = blockIdx.x * 4 + seg;
    const int* tg = tags + (size_t)b * 512;
    float num = 0.f;
    for (int t = kp; t < 512; t += 16) {
        int cur = tg[t];
        float e = em[((size_t)t * 64 + b) * 16 + cur];
        float tr = (t == 0) ? start_trans[cur] : trans[tg[t - 1] * 11 + cur];
        num += e + tr;
    }
#pragma unroll
    for (int off = 8; off >= 1; off >>= 1) num += __shfl_down(num, off, 16);
    float trcol[11];
#pragma unroll
    for (int k = 0; k < 11; k++) trcol[k] = trans[k * 11 + kpc];
    float s = start_trans[kpc] + em[(size_t)b * 16 + kpc];
    float em_nxt = em[((size_t)1 * 64 + b) * 16 + kpc];
    for (int t = 1; t < 512; ++t) {
        float em_t = em_nxt;
        int tn = (t + 1 < 512) ? t + 1 : t;
        em_nxt = em[((size_t)tn * 64 + b) * 16 + kpc];
        float v[11], m = -1e30f;
#pragma unroll
        for (int k = 0; k < 11; k++) {
            v[k] = __shfl(s, k, 16) + trcol[k];
            m = fmaxf(m, v[k]);
        }
        float sum = 0.f;
#pragma unroll
        for (int k = 0; k < 11; k++) sum += __expf(v[k] - m);
        s = m + __logf(sum) + em_t;
    }
    float u = s + end_trans[kpc];
    float m2 = -1e30f, vv[11];
#pragma unroll
    for (int k = 0; k < 11; k++) {
        vv[k] = __shfl(u, k, 16);
        m2 = fmaxf(m2, vv[k]);
    }
    float s2 = 0.f;
#pragma unroll
    for (int k = 0; k < 11; k++) s2 += __expf(vv[k] - m2);
    float den = m2 + __logf(s2);
    if (kp == 0) {
        float numt = num + end_trans[tg[511]];
        pb[b] = numt - den;
    }
}

__global__ __launch_bounds__(64) void final_kernel(const float* __restrict__ pb, float* __restrict__ out) {
    float v = pb[threadIdx.x];
#pragma unroll
    for (int off = 32; off >= 1; off >>= 1) v += __shfl_down(v, off, 64);
    if (threadIdx.x == 0) out[0] = -(v / 64.f);
}

// ---------- launch ----------
extern "C" void kernel_launch(void* const* d_in, const int* in_sizes, int n_in,
                              void* d_out, int out_size, void* d_ws, size_t ws_size,
                              hipStream_t stream) {
    const float* embeds = (const float*)d_in[0];
    const int* tags = (const int*)d_in[1];
    const float* wih0f = (const float*)d_in[3];
    const float* whh0f = (const float*)d_in[4];
    const float* bih0f = (const float*)d_in[5];
    const float* bhh0f = (const float*)d_in[6];
    const float* wih0r = (const float*)d_in[7];
    const float* whh0r = (const float*)d_in[8];
    const float* bih0r = (const float*)d_in[9];
    const float* bhh0r = (const float*)d_in[10];
    const float* wih1f = (const float*)d_in[11];
    const float* whh1f = (const float*)d_in[12];
    const float* bih1f = (const float*)d_in[13];
    const float* bhh1f = (const float*)d_in[14];
    const float* wih1r = (const float*)d_in[15];
    const float* whh1r = (const float*)d_in[16];
    const float* bih1r = (const float*)d_in[17];
    const float* bhh1r = (const float*)d_in[18];
    const float* lw = (const float*)d_in[19];
    const float* lb = (const float*)d_in[20];
    const float* st = (const float*)d_in[21];
    const float* et = (const float*)d_in[22];
    const float* tr = (const float*)d_in[23];
    float* out = (float*)d_out;

    char* ws = (char*)d_ws;
    u16* xproj = (u16*)(ws + 0);            // 64MB
    u16* h0 = (u16*)(ws + 67108864);        // 16MB
    u16* h1 = (u16*)(ws + 83886080);        // 16MB
    float* em = (float*)(ws + 100663296);   // 2MB
    u16* w0c = (u16*)(ws + 102760448);
    u16* w1c = (u16*)(ws + 104333312);
    float* pb = (float*)(ws + 104857600);

    convw_kernel<<<3072, 256, 0, stream>>>(wih0f, wih0r, w0c, 512, 768);
    convw_kernel<<<1024, 256, 0, stream>>>(wih1f, wih1r, w1c, 512, 256);
    gemm_lds<true><<<dim3(8, 256), 256, 0, stream>>>(embeds, w0c, xproj, 32768, 1024, 768);
    lstm_mfma<<<dim3(32, 2), 256, 0, stream>>>(xproj, whh0f, whh0r, bih0f, bhh0f, bih0r, bhh0r, h0);
    gemm_lds<false><<<dim3(8, 256), 256, 0, stream>>>(h0, w1c, xproj, 32768, 1024, 256);
    lstm_mfma<<<dim3(32, 2), 256, 0, stream>>>(xproj, whh1f, whh1r, bih1f, bhh1f, bih1r, bhh1r, h1);
    em_kernel<<<128, 256, 0, stream>>>(h1, lw, lb, em);
    crf_kernel<<<16, 64, 0, stream>>>(em, tags, st, et, tr, pb);
    final_kernel<<<1, 64, 0, stream>>>(pb, out);
}